// Round 5
// baseline (24360.597 us; speedup 1.0000x reference)
//
#include <hip/hip_runtime.h>
#include <math.h>
#include <stdint.h>

#define T_SEQ 4096

__device__ __forceinline__ float sigm(float x) { return 1.0f / (1.0f + expf(-x)); }

// ---------------------------------------------------------------------------
// Fence-free grid barrier, called by WAVE 0 ONLY (t < 64), direct polling.
// bar[g*32] (g=0..15): arrival counter for group g (16 blocks/group), monotonic.
// Arrival: lane 0 of each block does one relaxed agent RMW on its group line.
// Detect: lanes 0..15 of EVERY block poll the 16 counters in parallel; the
// wave reconverges when all 16 have reached 16*ord. No root, no release
// stage — two fewer LLC hops than R3. All transport is relaxed agent-scope
// atomics (empirically LLC-coherent on gfx950, proven R1-R3); no fences.
// ---------------------------------------------------------------------------
__device__ __forceinline__ void wave0_barrier(uint32_t* bar, uint32_t ord, int t) {
    if (t == 0)
        __hip_atomic_fetch_add(bar + ((blockIdx.x >> 4) << 5), 1u,
                               __ATOMIC_RELAXED, __HIP_MEMORY_SCOPE_AGENT);
    if (t < 16) {
        const uint32_t target = ord << 4;
        uint32_t* cnt = bar + (t << 5);
        while (__hip_atomic_load(cnt, __ATOMIC_RELAXED, __HIP_MEMORY_SCOPE_AGENT) < target)
            __builtin_amdgcn_s_sleep(1);
    }
}

// ---------------------------------------------------------------------------
// fp32 NT GEMM with bias: layer-0 preactivations for both branches.
// C[m][p(j)] = sum_k A[m][k]*B[j][k] + bias1[j]+bias2[j]
// Column permutation p(j): j = gate*1024 + 4b+u  ->  b*16 + gate*4 + u, so
// each recurrence block's 16 gate preacts are one contiguous 64 B line.
// ---------------------------------------------------------------------------
__global__ void __launch_bounds__(256) gemm_nt_bias(
    const float* __restrict__ A0, const float* __restrict__ A1,
    const float* __restrict__ B,
    const float* __restrict__ bias1, const float* __restrict__ bias2,
    float* __restrict__ C)
{
    const int t  = threadIdx.x;
    const int tx = t & 15, ty = t >> 4;
    const int n0 = blockIdx.x * 128, m0 = blockIdx.y * 128;
    const float* Ab = (m0 < 4096) ? A0 : A1;
    const int ml0 = (m0 < 4096) ? m0 : (m0 - 4096);

    __shared__ float As[16 * 140];
    __shared__ float Bs[16 * 140];

    const int lr = t >> 1;
    const int lh = t & 1;
    const int pw = lr + ((lr >> 5) << 2);
    const int pa = ty * 8 + ((ty >> 2) << 2);
    const int pb = tx * 8 + ((tx >> 2) << 2);

    float acc[8][8];
#pragma unroll
    for (int i = 0; i < 8; ++i)
#pragma unroll
        for (int j = 0; j < 8; ++j) acc[i][j] = 0.f;

    for (int k0 = 0; k0 < 1024; k0 += 16) {
        const float* ap = Ab + (size_t)(ml0 + lr) * 1024 + k0 + lh * 8;
        float4 av0 = *(const float4*)ap;
        float4 av1 = *(const float4*)(ap + 4);
        const float* bp = B + (size_t)(n0 + lr) * 1024 + k0 + lh * 8;
        float4 bv0 = *(const float4*)bp;
        float4 bv1 = *(const float4*)(bp + 4);

        __syncthreads();
        const int kb = lh * 8;
        As[(kb + 0) * 140 + pw] = av0.x;  As[(kb + 1) * 140 + pw] = av0.y;
        As[(kb + 2) * 140 + pw] = av0.z;  As[(kb + 3) * 140 + pw] = av0.w;
        As[(kb + 4) * 140 + pw] = av1.x;  As[(kb + 5) * 140 + pw] = av1.y;
        As[(kb + 6) * 140 + pw] = av1.z;  As[(kb + 7) * 140 + pw] = av1.w;
        Bs[(kb + 0) * 140 + pw] = bv0.x;  Bs[(kb + 1) * 140 + pw] = bv0.y;
        Bs[(kb + 2) * 140 + pw] = bv0.z;  Bs[(kb + 3) * 140 + pw] = bv0.w;
        Bs[(kb + 4) * 140 + pw] = bv1.x;  Bs[(kb + 5) * 140 + pw] = bv1.y;
        Bs[(kb + 6) * 140 + pw] = bv1.z;  Bs[(kb + 7) * 140 + pw] = bv1.w;
        __syncthreads();

#pragma unroll
        for (int kk = 0; kk < 16; ++kk) {
            float4 a0 = *(const float4*)&As[kk * 140 + pa];
            float4 a1 = *(const float4*)&As[kk * 140 + pa + 4];
            float4 b0 = *(const float4*)&Bs[kk * 140 + pb];
            float4 b1 = *(const float4*)&Bs[kk * 140 + pb + 4];
            float a[8]  = {a0.x, a0.y, a0.z, a0.w, a1.x, a1.y, a1.z, a1.w};
            float bb[8] = {b0.x, b0.y, b0.z, b0.w, b1.x, b1.y, b1.z, b1.w};
#pragma unroll
            for (int i = 0; i < 8; ++i)
#pragma unroll
                for (int j = 0; j < 8; ++j)
                    acc[i][j] = fmaf(a[i], bb[j], acc[i][j]);
        }
    }

    const int gcol  = n0 >> 10;              // gate for this whole block-column
    const int qbase = (n0 & 1023) + tx * 8;  // 4b+u base
    const int j0 = n0 + tx * 8;
    float bsv[8];
#pragma unroll
    for (int j = 0; j < 8; ++j) bsv[j] = bias1[j0 + j] + bias2[j0 + j];
#pragma unroll
    for (int i = 0; i < 8; ++i) {
        const size_t rowoff = (size_t)(m0 + ty * 8 + i) * 4096;
#pragma unroll
        for (int jj = 0; jj < 8; ++jj) {
            const int q = qbase + jj;
            C[rowoff + ((q >> 2) << 4) + (gcol << 2) + (q & 3)] = acc[i][jj] + bsv[jj];
        }
    }
}

// ---------------------------------------------------------------------------
// Fused layer-pipelined LSTM recurrence (one cooperative dispatch).
// 256 blocks x 256 threads. Tick tau: layer0 step tau, layer1 step tau-1.
// hbuf layout (per 4096-float buffer): [block][16] where i = layer*8+br*4+u,
// so each block's h contribution is one contiguous 64 B line -> single
// coalesced producer store, 64-bit consumer loads + LDS transpose.
// Cross-block h transport: relaxed agent atomics (proven coherent). No fences.
// ---------------------------------------------------------------------------
__global__ void __launch_bounds__(256, 1) lstm_fused(
    const float* __restrict__ W_hh,  // [2][4096][1024]
    const float* __restrict__ W_ih,  // [2][4096][1024]
    const float* __restrict__ b_ih,  // [2][4096]
    const float* __restrict__ b_hh,  // [2][4096]
    const float* __restrict__ G,     // [2 br][T][4096] permuted layer-0 preacts
    const float* __restrict__ h1_0, const float* __restrict__ c1_0,
    const float* __restrict__ h2_0, const float* __restrict__ c2_0,
    float* __restrict__ hbuf,        // [2 buf][256 blk][16]
    float* __restrict__ o_out,       // [2 br][1024]
    uint32_t* __restrict__ bar)
{
    const int b = blockIdx.x, t = threadIdx.x;
    const int row = t & 15, slice = t >> 4;
    const int gate = row >> 2, uoff = row & 3;
    const int j_glob = gate * 1024 + b * 4 + uoff;

    // ---- weights -> registers (rotated to match LDS traversal) ----
    float4 w0[16], w1h[16], w1i[16];
    {
        const float* r0 = W_hh + (size_t)j_glob * 1024 + slice * 64;
        const float* r1 = W_hh + 4194304ull + (size_t)j_glob * 1024 + slice * 64;
        const float* r2 = W_ih + 4194304ull + (size_t)j_glob * 1024 + slice * 64;
#pragma unroll
        for (int m = 0; m < 16; ++m) {
            const int o = ((m + slice) & 15) << 2;
            w0[m]  = *(const float4*)(r0 + o);
            w1h[m] = *(const float4*)(r1 + o);
            w1i[m] = *(const float4*)(r2 + o);
        }
    }

    __shared__ float hs[4096];        // [4 seg][1024]: seg = layer*2+br
    __shared__ float red[4][4][16];   // [wave][acc][row]
    __shared__ float bl1s[16];        // layer-1 bias for owned rows

    // ---- init: t<16 holds (layer=t>>3, br=(t>>2)&1, u=t&3); i == t ----
    float creg = 0.f;
    if (t < 16) {
        const int layer = t >> 3, br = (t >> 2) & 1;
        const float* cc = br ? c2_0 : c1_0;
        const float* hh = br ? h2_0 : h1_0;
        creg = cc[layer * 1024 + b * 4 + (t & 3)];
        const float hinit = hh[layer * 1024 + b * 4 + (t & 3)];
        __hip_atomic_store(&hbuf[4096 + b * 16 + t], hinit,
                           __ATOMIC_RELAXED, __HIP_MEMORY_SCOPE_AGENT);   // buf1
        if (layer == 1)
            __hip_atomic_store(&hbuf[b * 16 + t], hinit,
                               __ATOMIC_RELAXED, __HIP_MEMORY_SCOPE_AGENT); // buf0
    }
    if (t >= 32 && t < 48) {
        const int rr = t & 15;
        const int jj = 4096 + (rr >> 2) * 1024 + b * 4 + (rr & 3);
        bl1s[rr] = b_ih[jj] + b_hh[jj];
    }
    if (t < 64) {
        asm volatile("s_waitcnt vmcnt(0)" ::: "memory");
        wave0_barrier(bar, 1u, t);
    }
    __syncthreads();

    // staging transpose constants: thread t handles u64 elements r*256+t,
    // covering floats F=r*512+2t .. F+1; blk=r*32+(t>>3), seg=(t&7)>>1,
    // u=2*((t&7)&1) -> hs64 dst = seg*512 + blk*2 + (t&1 of k)
    const int q_st = t >> 3, k_st = t & 7;
    const int dst_base = (k_st >> 1) * 512 + q_st * 2 + (k_st & 1);

    for (int tick = 0; tick <= T_SEQ; ++tick) {
        // ---- stage h_prev (16 KB) LLC -> LDS via 64-bit relaxed atomics ----
        {
            const uint64_t* src64 = (const uint64_t*)(hbuf + ((tick + 1) & 1) * 4096);
            uint64_t v[8];
#pragma unroll
            for (int r = 0; r < 8; ++r)
                v[r] = __hip_atomic_load(src64 + r * 256 + t, __ATOMIC_RELAXED,
                                         __HIP_MEMORY_SCOPE_AGENT);
            uint64_t* hs64 = (uint64_t*)hs;
#pragma unroll
            for (int r = 0; r < 8; ++r)
                hs64[dst_base + r * 64] = v[r];
        }
        // ---- layer-0 G prefetch: lane t<32 gets row rr of branch t>>4 ----
        float gpre = 0.f;
        if (t < 32) {
            const int br = t >> 4, rr = t & 15;
            const int st = (tick < T_SEQ) ? tick : (T_SEQ - 1);
            gpre = G[((size_t)br * T_SEQ + st) * 4096 + b * 16 + rr];
        }
        __syncthreads();

        // ---- 3 matvecs over owned rows ----
        float a00 = 0.f, a01 = 0.f, a10 = 0.f, a11 = 0.f;
        const float4* H00 = (const float4*)hs;
        const float4* H01 = (const float4*)(hs + 1024);
        const float4* H10 = (const float4*)(hs + 2048);
        const float4* H11 = (const float4*)(hs + 3072);
#pragma unroll
        for (int m = 0; m < 16; ++m) {
            const int ci = (slice << 4) + ((m + slice) & 15);
            const float4 x0 = H00[ci], x1 = H01[ci];
            const float4 y0 = H10[ci], y1 = H11[ci];
            a00 = fmaf(w0[m].x, x0.x, a00); a00 = fmaf(w0[m].y, x0.y, a00);
            a00 = fmaf(w0[m].z, x0.z, a00); a00 = fmaf(w0[m].w, x0.w, a00);
            a01 = fmaf(w0[m].x, x1.x, a01); a01 = fmaf(w0[m].y, x1.y, a01);
            a01 = fmaf(w0[m].z, x1.z, a01); a01 = fmaf(w0[m].w, x1.w, a01);
            a10 = fmaf(w1i[m].x, x0.x, a10); a10 = fmaf(w1i[m].y, x0.y, a10);
            a10 = fmaf(w1i[m].z, x0.z, a10); a10 = fmaf(w1i[m].w, x0.w, a10);
            a10 = fmaf(w1h[m].x, y0.x, a10); a10 = fmaf(w1h[m].y, y0.y, a10);
            a10 = fmaf(w1h[m].z, y0.z, a10); a10 = fmaf(w1h[m].w, y0.w, a10);
            a11 = fmaf(w1i[m].x, x1.x, a11); a11 = fmaf(w1i[m].y, x1.y, a11);
            a11 = fmaf(w1i[m].z, x1.z, a11); a11 = fmaf(w1i[m].w, x1.w, a11);
            a11 = fmaf(w1h[m].x, y1.x, a11); a11 = fmaf(w1h[m].y, y1.y, a11);
            a11 = fmaf(w1h[m].w, y1.w, a11); a11 = fmaf(w1h[m].z, y1.z, a11);
        }
        a00 += __shfl_xor(a00, 16); a00 += __shfl_xor(a00, 32);
        a01 += __shfl_xor(a01, 16); a01 += __shfl_xor(a01, 32);
        a10 += __shfl_xor(a10, 16); a10 += __shfl_xor(a10, 32);
        a11 += __shfl_xor(a11, 16); a11 += __shfl_xor(a11, 32);
        const int wv = t >> 6, lane = t & 63;
        if (lane < 16) {
            red[wv][0][lane] = a00; red[wv][1][lane] = a01;
            red[wv][2][lane] = a10; red[wv][3][lane] = a11;
        }
        __syncthreads();

        // ---- tail: wave 0 only ----
        if (t < 64) {
            const int lb = t >> 4, rr = t & 15;
            float s = red[0][lb][rr] + red[1][lb][rr] + red[2][lb][rr] + red[3][lb][rr];
            s += (lb < 2) ? gpre : bl1s[rr];
            // lane lb*16+rr holds gate (rr>>2) of unit (rr&3), layer=lb>>1, br=lb&1
            const int src0 = ((t >> 2) << 4) + (t & 3);   // meaningful for t<16
            const float gi = __shfl(s, src0);
            const float gf = __shfl(s, src0 + 4);
            const float gg = __shfl(s, src0 + 8);
            const float go = __shfl(s, src0 + 12);
            if (t < 16) {
                const int layer = t >> 3, br = (t >> 2) & 1, u = t & 3;
                const bool active = (layer == 0) ? (tick < T_SEQ) : (tick >= 1);
                if (active) {
                    const float c = sigm(gf) * creg + sigm(gi) * tanhf(gg);
                    const float h = sigm(go) * tanhf(c);
                    creg = c;
                    __hip_atomic_store(&hbuf[(tick & 1) * 4096 + b * 16 + t], h,
                                       __ATOMIC_RELAXED, __HIP_MEMORY_SCOPE_AGENT);
                    if (layer == 1 && tick == T_SEQ)
                        o_out[br * 1024 + b * 4 + u] = h;
                }
            }
            if (tick < T_SEQ) {
                asm volatile("s_waitcnt vmcnt(0)" ::: "memory");  // h at LLC
                wave0_barrier(bar, (uint32_t)tick + 2u, t);
            }
        }
        __syncthreads();
    }
}

// ---------------------------------------------------------------------------
// out = 5*exp(-sum |o1 - o2|)
// ---------------------------------------------------------------------------
__global__ void __launch_bounds__(256) dist_kernel(const float* __restrict__ o,
                                                   float* __restrict__ out)
{
    int t = threadIdx.x;
    float s = 0.f;
    for (int i = t; i < 1024; i += 256) s += fabsf(o[i] - o[i + 1024]);
#pragma unroll
    for (int off = 1; off < 64; off <<= 1) s += __shfl_xor(s, off);
    __shared__ float r[4];
    if ((t & 63) == 0) r[t >> 6] = s;
    __syncthreads();
    if (t == 0) out[0] = 5.0f * expf(-(r[0] + r[1] + r[2] + r[3]));
}

// ---------------------------------------------------------------------------
extern "C" void kernel_launch(void* const* d_in, const int* in_sizes, int n_in,
                              void* d_out, int out_size, void* d_ws, size_t ws_size,
                              hipStream_t stream) {
    const float* s1   = (const float*)d_in[0];
    const float* s2   = (const float*)d_in[1];
    const float* h1_0 = (const float*)d_in[2];
    const float* c1_0 = (const float*)d_in[3];
    const float* h2_0 = (const float*)d_in[4];
    const float* c2_0 = (const float*)d_in[5];
    const float* W_ih = (const float*)d_in[6];
    const float* W_hh = (const float*)d_in[7];
    const float* b_ih = (const float*)d_in[8];
    const float* b_hh = (const float*)d_in[9];

    uint8_t* w8 = (uint8_t*)d_ws;
    uint32_t* bar  = (uint32_t*)(w8);            // 8 KB barrier region
    float* hbuf  = (float*)(w8 + 8192);          // 32 KB: [2][256][16]
    float* o_out = (float*)(w8 + 8192 + 32768);  // 8 KB:  [2][1024]
    float* G     = (float*)(w8 + 65536);         // 128 MB: [2][T][4096]

    hipMemsetAsync(d_ws, 0, 8192, stream);       // zero barrier counters

    // Phase 1: layer-0 input GEMM for both branches (permuted output)
    dim3 ggrid(32, 64);
    gemm_nt_bias<<<ggrid, 256, 0, stream>>>(s1, s2, W_ih, b_ih, b_hh, G);

    // Phase 2: fused layer-pipelined recurrence (single cooperative dispatch)
    {
        const float* whh = W_hh; const float* wih = W_ih;
        const float* bi = b_ih;  const float* bh = b_hh;
        const float* gg = G;
        const float* h1p = h1_0; const float* c1p = c1_0;
        const float* h2p = h2_0; const float* c2p = c2_0;
        float* hb = hbuf; float* oo = o_out; uint32_t* br = bar;
        void* args[] = { &whh, &wih, &bi, &bh, &gg,
                         &h1p, &c1p, &h2p, &c2p, &hb, &oo, &br };
        hipLaunchCooperativeKernel(lstm_fused, dim3(256), dim3(256), args, 0, stream);
    }

    // Phase 3: scalar output
    dist_kernel<<<1, 256, 0, stream>>>(o_out, (float*)d_out);
}

// Round 6
// 17498.087 us; speedup vs baseline: 1.3922x; 1.3922x over previous
//
#include <hip/hip_runtime.h>
#include <math.h>
#include <stdint.h>

#define T_SEQ 4096

// Fast activations (on the serial tail critical path). __expf error ~2 ulp;
// feeds a contracting recurrence -> final error << 2% threshold (R3 margin
// was absmax 0.0 with exact libm).
__device__ __forceinline__ float sigm(float x) { return 1.0f / (1.0f + __expf(-x)); }
__device__ __forceinline__ float ftanh(float x) {
    return 1.0f - 2.0f / (__expf(2.0f * x) + 1.0f);   // +-inf-safe: -> +-1
}

// ---------------------------------------------------------------------------
// Last-arriver tree barrier, wave 0 only. NO detect-poll stage:
//   bar[g*32]        g=0..15 : group arrival counters (16 blocks each)
//   bar[512 + g*32]          : release words (16 pollers each — R3-proven OK)
//   bar[1024]                : root counter (16 group-closers per ord)
// Arrival RMW returns old value; old == 16*ord-1 identifies the closer at
// both levels. Root closer broadcasts ord to all 16 release words (lanes
// 0..15, one coalesced-ish store each). Everyone polls own release word.
// All relaxed agent-scope atomics (LLC-coherent on gfx950, proven R1-R4);
// no fences anywhere. Polling discipline: <=16 pollers/line (R0/R4 flood
// lesson), arrival lines are never polled.
// ---------------------------------------------------------------------------
__device__ __forceinline__ void wave0_barrier(uint32_t* bar, uint32_t ord, int t) {
    int rootclose = 0;
    if (t == 0) {
        const uint32_t tgt = (ord << 4) - 1u;
        uint32_t old = __hip_atomic_fetch_add(bar + ((blockIdx.x >> 4) << 5), 1u,
                                              __ATOMIC_RELAXED, __HIP_MEMORY_SCOPE_AGENT);
        if (old == tgt) {   // closed this group
            uint32_t rold = __hip_atomic_fetch_add(bar + 1024, 1u,
                                                   __ATOMIC_RELAXED, __HIP_MEMORY_SCOPE_AGENT);
            rootclose = (rold == tgt);   // closed the root: all 256 arrived
        }
    }
    rootclose = __shfl(rootclose, 0);
    if (rootclose && t < 16)
        __hip_atomic_store(bar + 512 + (t << 5), ord,
                           __ATOMIC_RELAXED, __HIP_MEMORY_SCOPE_AGENT);
    if (t == 0) {
        uint32_t* rel = bar + 512 + ((blockIdx.x >> 4) << 5);
        while (__hip_atomic_load(rel, __ATOMIC_RELAXED, __HIP_MEMORY_SCOPE_AGENT) < ord)
            __builtin_amdgcn_s_sleep(1);
    }
}

// ---------------------------------------------------------------------------
// fp32 NT GEMM with bias: layer-0 preactivations for both branches.
// C[m][p(j)] = sum_k A[m][k]*B[j][k] + bias1[j]+bias2[j]
// Column permutation p(j): j = gate*1024 + 4b+u  ->  b*16 + gate*4 + u, so
// each recurrence block's 16 gate preacts are one contiguous 64 B line.
// ---------------------------------------------------------------------------
__global__ void __launch_bounds__(256) gemm_nt_bias(
    const float* __restrict__ A0, const float* __restrict__ A1,
    const float* __restrict__ B,
    const float* __restrict__ bias1, const float* __restrict__ bias2,
    float* __restrict__ C)
{
    const int t  = threadIdx.x;
    const int tx = t & 15, ty = t >> 4;
    const int n0 = blockIdx.x * 128, m0 = blockIdx.y * 128;
    const float* Ab = (m0 < 4096) ? A0 : A1;
    const int ml0 = (m0 < 4096) ? m0 : (m0 - 4096);

    __shared__ float As[16 * 140];
    __shared__ float Bs[16 * 140];

    const int lr = t >> 1;
    const int lh = t & 1;
    const int pw = lr + ((lr >> 5) << 2);
    const int pa = ty * 8 + ((ty >> 2) << 2);
    const int pb = tx * 8 + ((tx >> 2) << 2);

    float acc[8][8];
#pragma unroll
    for (int i = 0; i < 8; ++i)
#pragma unroll
        for (int j = 0; j < 8; ++j) acc[i][j] = 0.f;

    for (int k0 = 0; k0 < 1024; k0 += 16) {
        const float* ap = Ab + (size_t)(ml0 + lr) * 1024 + k0 + lh * 8;
        float4 av0 = *(const float4*)ap;
        float4 av1 = *(const float4*)(ap + 4);
        const float* bp = B + (size_t)(n0 + lr) * 1024 + k0 + lh * 8;
        float4 bv0 = *(const float4*)bp;
        float4 bv1 = *(const float4*)(bp + 4);

        __syncthreads();
        const int kb = lh * 8;
        As[(kb + 0) * 140 + pw] = av0.x;  As[(kb + 1) * 140 + pw] = av0.y;
        As[(kb + 2) * 140 + pw] = av0.z;  As[(kb + 3) * 140 + pw] = av0.w;
        As[(kb + 4) * 140 + pw] = av1.x;  As[(kb + 5) * 140 + pw] = av1.y;
        As[(kb + 6) * 140 + pw] = av1.z;  As[(kb + 7) * 140 + pw] = av1.w;
        Bs[(kb + 0) * 140 + pw] = bv0.x;  Bs[(kb + 1) * 140 + pw] = bv0.y;
        Bs[(kb + 2) * 140 + pw] = bv0.z;  Bs[(kb + 3) * 140 + pw] = bv0.w;
        Bs[(kb + 4) * 140 + pw] = bv1.x;  Bs[(kb + 5) * 140 + pw] = bv1.y;
        Bs[(kb + 6) * 140 + pw] = bv1.z;  Bs[(kb + 7) * 140 + pw] = bv1.w;
        __syncthreads();

#pragma unroll
        for (int kk = 0; kk < 16; ++kk) {
            float4 a0 = *(const float4*)&As[kk * 140 + pa];
            float4 a1 = *(const float4*)&As[kk * 140 + pa + 4];
            float4 b0 = *(const float4*)&Bs[kk * 140 + pb];
            float4 b1 = *(const float4*)&Bs[kk * 140 + pb + 4];
            float a[8]  = {a0.x, a0.y, a0.z, a0.w, a1.x, a1.y, a1.z, a1.w};
            float bb[8] = {b0.x, b0.y, b0.z, b0.w, b1.x, b1.y, b1.z, b1.w};
#pragma unroll
            for (int i = 0; i < 8; ++i)
#pragma unroll
                for (int j = 0; j < 8; ++j)
                    acc[i][j] = fmaf(a[i], bb[j], acc[i][j]);
        }
    }

    const int gcol  = n0 >> 10;              // gate for this whole block-column
    const int qbase = (n0 & 1023) + tx * 8;  // 4b+u base
    const int j0 = n0 + tx * 8;
    float bsv[8];
#pragma unroll
    for (int j = 0; j < 8; ++j) bsv[j] = bias1[j0 + j] + bias2[j0 + j];
#pragma unroll
    for (int i = 0; i < 8; ++i) {
        const size_t rowoff = (size_t)(m0 + ty * 8 + i) * 4096;
#pragma unroll
        for (int jj = 0; jj < 8; ++jj) {
            const int q = qbase + jj;
            C[rowoff + ((q >> 2) << 4) + (gcol << 2) + (q & 3)] = acc[i][jj] + bsv[jj];
        }
    }
}

// ---------------------------------------------------------------------------
// Fused layer-pipelined LSTM recurrence (one cooperative dispatch).
// 256 blocks x 256 threads. Tick tau: layer0 step tau, layer1 step tau-1.
// hbuf layout: [2 buf][2 layer][2 br][1024] (R3-proven; 4x16B scatter store
// drains in one RTT since vmcnt is wave-level).
// Cross-block h transport: relaxed agent atomics (proven coherent). No fences.
// ---------------------------------------------------------------------------
__global__ void __launch_bounds__(256, 1) lstm_fused(
    const float* __restrict__ W_hh,  // [2][4096][1024]
    const float* __restrict__ W_ih,  // [2][4096][1024]
    const float* __restrict__ b_ih,  // [2][4096]
    const float* __restrict__ b_hh,  // [2][4096]
    const float* __restrict__ G,     // [2 br][T][4096] permuted layer-0 preacts
    const float* __restrict__ h1_0, const float* __restrict__ c1_0,
    const float* __restrict__ h2_0, const float* __restrict__ c2_0,
    float* __restrict__ hbuf,        // [2 buf][2 layer][2 br][1024]
    float* __restrict__ o_out,       // [2 br][1024]
    uint32_t* __restrict__ bar)
{
    const int b = blockIdx.x, t = threadIdx.x;
    const int row = t & 15, slice = t >> 4;
    const int gate = row >> 2, uoff = row & 3;
    const int j_glob = gate * 1024 + b * 4 + uoff;

    // ---- weights -> registers (rotated to match LDS traversal) ----
    float4 w0[16], w1h[16], w1i[16];
    {
        const float* r0 = W_hh + (size_t)j_glob * 1024 + slice * 64;
        const float* r1 = W_hh + 4194304ull + (size_t)j_glob * 1024 + slice * 64;
        const float* r2 = W_ih + 4194304ull + (size_t)j_glob * 1024 + slice * 64;
#pragma unroll
        for (int m = 0; m < 16; ++m) {
            const int o = ((m + slice) & 15) << 2;
            w0[m]  = *(const float4*)(r0 + o);
            w1h[m] = *(const float4*)(r1 + o);
            w1i[m] = *(const float4*)(r2 + o);
        }
    }

    __shared__ float hs[4096];        // [4 seg][1024]: seg = layer*2+br
    __shared__ float red[4][4][16];   // [wave][acc][row]
    __shared__ float bl1s[16];        // layer-1 bias for owned rows

    float creg = 0.f;
    if (t < 16) {
        const int layer = t >> 3, br = (t >> 2) & 1, u = t & 3;
        const float* cc = br ? c2_0 : c1_0;
        const float* hh = br ? h2_0 : h1_0;
        creg = cc[layer * 1024 + b * 4 + u];
        const float hinit = hh[layer * 1024 + b * 4 + u];
        __hip_atomic_store(&hbuf[4096 + layer * 2048 + br * 1024 + b * 4 + u],
                           hinit, __ATOMIC_RELAXED, __HIP_MEMORY_SCOPE_AGENT);
        if (layer == 1)
            __hip_atomic_store(&hbuf[2048 + br * 1024 + b * 4 + u],
                               hinit, __ATOMIC_RELAXED, __HIP_MEMORY_SCOPE_AGENT);
    }
    if (t >= 32 && t < 48) {
        const int rr = t & 15;
        const int jj = 4096 + (rr >> 2) * 1024 + b * 4 + (rr & 3);
        bl1s[rr] = b_ih[jj] + b_hh[jj];
    }
    if (t < 64) {
        asm volatile("s_waitcnt vmcnt(0)" ::: "memory");
        wave0_barrier(bar, 1u, t);
    }
    __syncthreads();

    for (int tick = 0; tick <= T_SEQ; ++tick) {
        // ---- stage h_prev (16 KB) LLC -> LDS via relaxed agent atomic loads ----
        {
            const float* src = hbuf + ((tick + 1) & 1) * 4096;
            float v[16];
#pragma unroll
            for (int r = 0; r < 16; ++r)
                v[r] = __hip_atomic_load(src + t + r * 256, __ATOMIC_RELAXED,
                                         __HIP_MEMORY_SCOPE_AGENT);
#pragma unroll
            for (int r = 0; r < 16; ++r)
                hs[t + r * 256] = v[r];
        }
        // ---- layer-0 G prefetch: lane t<32 gets row rr of branch t>>4 ----
        float gpre = 0.f;
        if (t < 32) {
            const int br = t >> 4, rr = t & 15;
            const int st = (tick < T_SEQ) ? tick : (T_SEQ - 1);
            gpre = G[((size_t)br * T_SEQ + st) * 4096 + b * 16 + rr];
        }
        __syncthreads();

        // ---- 3 matvecs over owned rows ----
        float a00 = 0.f, a01 = 0.f, a10 = 0.f, a11 = 0.f;
        const float4* H00 = (const float4*)hs;
        const float4* H01 = (const float4*)(hs + 1024);
        const float4* H10 = (const float4*)(hs + 2048);
        const float4* H11 = (const float4*)(hs + 3072);
#pragma unroll
        for (int m = 0; m < 16; ++m) {
            const int ci = (slice << 4) + ((m + slice) & 15);
            const float4 x0 = H00[ci], x1 = H01[ci];
            const float4 y0 = H10[ci], y1 = H11[ci];
            a00 = fmaf(w0[m].x, x0.x, a00); a00 = fmaf(w0[m].y, x0.y, a00);
            a00 = fmaf(w0[m].z, x0.z, a00); a00 = fmaf(w0[m].w, x0.w, a00);
            a01 = fmaf(w0[m].x, x1.x, a01); a01 = fmaf(w0[m].y, x1.y, a01);
            a01 = fmaf(w0[m].z, x1.z, a01); a01 = fmaf(w0[m].w, x1.w, a01);
            a10 = fmaf(w1i[m].x, x0.x, a10); a10 = fmaf(w1i[m].y, x0.y, a10);
            a10 = fmaf(w1i[m].z, x0.z, a10); a10 = fmaf(w1i[m].w, x0.w, a10);
            a10 = fmaf(w1h[m].x, y0.x, a10); a10 = fmaf(w1h[m].y, y0.y, a10);
            a10 = fmaf(w1h[m].z, y0.z, a10); a10 = fmaf(w1h[m].w, y0.w, a10);
            a11 = fmaf(w1i[m].x, x1.x, a11); a11 = fmaf(w1i[m].y, x1.y, a11);
            a11 = fmaf(w1i[m].z, x1.z, a11); a11 = fmaf(w1i[m].w, x1.w, a11);
            a11 = fmaf(w1h[m].x, y1.x, a11); a11 = fmaf(w1h[m].y, y1.y, a11);
            a11 = fmaf(w1h[m].z, y1.z, a11); a11 = fmaf(w1h[m].w, y1.w, a11);
        }
        a00 += __shfl_xor(a00, 16); a00 += __shfl_xor(a00, 32);
        a01 += __shfl_xor(a01, 16); a01 += __shfl_xor(a01, 32);
        a10 += __shfl_xor(a10, 16); a10 += __shfl_xor(a10, 32);
        a11 += __shfl_xor(a11, 16); a11 += __shfl_xor(a11, 32);
        const int wv = t >> 6, lane = t & 63;
        if (lane < 16) {
            red[wv][0][lane] = a00; red[wv][1][lane] = a01;
            red[wv][2][lane] = a10; red[wv][3][lane] = a11;
        }
        __syncthreads();

        // ---- tail: wave 0 only ----
        if (t < 64) {
            const int lb = t >> 4, rr = t & 15;
            float s = red[0][lb][rr] + red[1][lb][rr] + red[2][lb][rr] + red[3][lb][rr];
            s += (lb < 2) ? gpre : bl1s[rr];
            // lane lb*16+rr holds gate (rr>>2) of unit (rr&3), layer=lb>>1, br=lb&1
            const int src0 = ((t >> 2) << 4) + (t & 3);   // meaningful for t<16
            const float gi = __shfl(s, src0);
            const float gf = __shfl(s, src0 + 4);
            const float gg = __shfl(s, src0 + 8);
            const float go = __shfl(s, src0 + 12);
            if (t < 16) {
                const int layer = t >> 3, br = (t >> 2) & 1, u = t & 3;
                const bool active = (layer == 0) ? (tick < T_SEQ) : (tick >= 1);
                if (active) {
                    const float c = sigm(gf) * creg + sigm(gi) * ftanh(gg);
                    const float h = sigm(go) * ftanh(c);
                    creg = c;
                    __hip_atomic_store(&hbuf[(tick & 1) * 4096 + layer * 2048 + br * 1024 + b * 4 + u],
                                       h, __ATOMIC_RELAXED, __HIP_MEMORY_SCOPE_AGENT);
                    if (layer == 1 && tick == T_SEQ)
                        o_out[br * 1024 + b * 4 + u] = h;
                }
            }
            if (tick < T_SEQ) {
                asm volatile("s_waitcnt vmcnt(0)" ::: "memory");  // h at LLC
                wave0_barrier(bar, (uint32_t)tick + 2u, t);
            }
        }
        __syncthreads();
    }
}

// ---------------------------------------------------------------------------
// out = 5*exp(-sum |o1 - o2|)
// ---------------------------------------------------------------------------
__global__ void __launch_bounds__(256) dist_kernel(const float* __restrict__ o,
                                                   float* __restrict__ out)
{
    int t = threadIdx.x;
    float s = 0.f;
    for (int i = t; i < 1024; i += 256) s += fabsf(o[i] - o[i + 1024]);
#pragma unroll
    for (int off = 1; off < 64; off <<= 1) s += __shfl_xor(s, off);
    __shared__ float r[4];
    if ((t & 63) == 0) r[t >> 6] = s;
    __syncthreads();
    if (t == 0) out[0] = 5.0f * expf(-(r[0] + r[1] + r[2] + r[3]));
}

// ---------------------------------------------------------------------------
extern "C" void kernel_launch(void* const* d_in, const int* in_sizes, int n_in,
                              void* d_out, int out_size, void* d_ws, size_t ws_size,
                              hipStream_t stream) {
    const float* s1   = (const float*)d_in[0];
    const float* s2   = (const float*)d_in[1];
    const float* h1_0 = (const float*)d_in[2];
    const float* c1_0 = (const float*)d_in[3];
    const float* h2_0 = (const float*)d_in[4];
    const float* c2_0 = (const float*)d_in[5];
    const float* W_ih = (const float*)d_in[6];
    const float* W_hh = (const float*)d_in[7];
    const float* b_ih = (const float*)d_in[8];
    const float* b_hh = (const float*)d_in[9];

    uint8_t* w8 = (uint8_t*)d_ws;
    uint32_t* bar  = (uint32_t*)(w8);            // 8 KB barrier region
    float* hbuf  = (float*)(w8 + 8192);          // 32 KB: [2][2][2][1024]
    float* o_out = (float*)(w8 + 8192 + 32768);  // 8 KB:  [2][1024]
    float* G     = (float*)(w8 + 65536);         // 128 MB: [2][T][4096]

    hipMemsetAsync(d_ws, 0, 8192, stream);       // zero barrier counters

    // Phase 1: layer-0 input GEMM for both branches (permuted output)
    dim3 ggrid(32, 64);
    gemm_nt_bias<<<ggrid, 256, 0, stream>>>(s1, s2, W_ih, b_ih, b_hh, G);

    // Phase 2: fused layer-pipelined recurrence (single cooperative dispatch)
    {
        const float* whh = W_hh; const float* wih = W_ih;
        const float* bi = b_ih;  const float* bh = b_hh;
        const float* gg = G;
        const float* h1p = h1_0; const float* c1p = c1_0;
        const float* h2p = h2_0; const float* c2p = c2_0;
        float* hb = hbuf; float* oo = o_out; uint32_t* br = bar;
        void* args[] = { &whh, &wih, &bi, &bh, &gg,
                         &h1p, &c1p, &h2p, &c2p, &hb, &oo, &br };
        hipLaunchCooperativeKernel(lstm_fused, dim3(256), dim3(256), args, 0, stream);
    }

    // Phase 3: scalar output
    dist_kernel<<<1, 256, 0, stream>>>(o_out, (float*)d_out);
}

// Round 7
// 17302.841 us; speedup vs baseline: 1.4079x; 1.0113x over previous
//
#include <hip/hip_runtime.h>
#include <math.h>
#include <stdint.h>

#define T_SEQ 4096

// Fast activations (serial tail critical path). __expf ~2 ulp; error through
// the contracting recurrence << 2% threshold (R5 passed with absmax 0.0).
__device__ __forceinline__ float sigm(float x) { return 1.0f / (1.0f + __expf(-x)); }
__device__ __forceinline__ float ftanh(float x) {
    return 1.0f - 2.0f / (__expf(2.0f * x) + 1.0f);   // +-inf-safe: -> +-1
}

// ---------------------------------------------------------------------------
// Fence-free grid barrier (R3 version — best measured), wave 0 only.
// bar[g*32]       : arrival counter, group g (16 blocks/group), monotonic
// bar[512 + g*32] : release word, group g (16 pollers/line max — R0/R4 flood
//                   lesson: never more)
// Block 0 lanes 0..15 poll the 16 group counters in parallel, then broadcast
// to the 16 release words. All transport relaxed agent-scope atomics
// (empirically LLC-coherent on gfx950, proven R1-R5); no fences.
// ---------------------------------------------------------------------------
__device__ __forceinline__ void wave0_barrier(uint32_t* bar, uint32_t ord, int t) {
    if (t == 0)
        __hip_atomic_fetch_add(bar + ((blockIdx.x >> 4) << 5), 1u,
                               __ATOMIC_RELAXED, __HIP_MEMORY_SCOPE_AGENT);
    if (blockIdx.x == 0) {
        if (t < 16) {
            uint32_t* cnt = bar + (t << 5);
            while (__hip_atomic_load(cnt, __ATOMIC_RELAXED, __HIP_MEMORY_SCOPE_AGENT) < (ord << 4))
                __builtin_amdgcn_s_sleep(1);
            __hip_atomic_store(bar + 512 + (t << 5), ord,
                               __ATOMIC_RELAXED, __HIP_MEMORY_SCOPE_AGENT);
        }
    } else if (t == 0) {
        uint32_t* rel = bar + 512 + ((blockIdx.x >> 4) << 5);
        while (__hip_atomic_load(rel, __ATOMIC_RELAXED, __HIP_MEMORY_SCOPE_AGENT) < ord)
            __builtin_amdgcn_s_sleep(1);
    }
}

// ---------------------------------------------------------------------------
// fp32 NT GEMM with bias: layer-0 preactivations for both branches.
// C[m][p(j)] = sum_k A[m][k]*B[j][k] + bias1[j]+bias2[j]
// Column permutation p(j): j = gate*1024 + 4b+u  ->  b*16 + gate*4 + u, so
// each recurrence block's 16 gate preacts are one contiguous 64 B line.
// ---------------------------------------------------------------------------
__global__ void __launch_bounds__(256) gemm_nt_bias(
    const float* __restrict__ A0, const float* __restrict__ A1,
    const float* __restrict__ B,
    const float* __restrict__ bias1, const float* __restrict__ bias2,
    float* __restrict__ C)
{
    const int t  = threadIdx.x;
    const int tx = t & 15, ty = t >> 4;
    const int n0 = blockIdx.x * 128, m0 = blockIdx.y * 128;
    const float* Ab = (m0 < 4096) ? A0 : A1;
    const int ml0 = (m0 < 4096) ? m0 : (m0 - 4096);

    __shared__ float As[16 * 140];
    __shared__ float Bs[16 * 140];

    const int lr = t >> 1;
    const int lh = t & 1;
    const int pw = lr + ((lr >> 5) << 2);
    const int pa = ty * 8 + ((ty >> 2) << 2);
    const int pb = tx * 8 + ((tx >> 2) << 2);

    float acc[8][8];
#pragma unroll
    for (int i = 0; i < 8; ++i)
#pragma unroll
        for (int j = 0; j < 8; ++j) acc[i][j] = 0.f;

    for (int k0 = 0; k0 < 1024; k0 += 16) {
        const float* ap = Ab + (size_t)(ml0 + lr) * 1024 + k0 + lh * 8;
        float4 av0 = *(const float4*)ap;
        float4 av1 = *(const float4*)(ap + 4);
        const float* bp = B + (size_t)(n0 + lr) * 1024 + k0 + lh * 8;
        float4 bv0 = *(const float4*)bp;
        float4 bv1 = *(const float4*)(bp + 4);

        __syncthreads();
        const int kb = lh * 8;
        As[(kb + 0) * 140 + pw] = av0.x;  As[(kb + 1) * 140 + pw] = av0.y;
        As[(kb + 2) * 140 + pw] = av0.z;  As[(kb + 3) * 140 + pw] = av0.w;
        As[(kb + 4) * 140 + pw] = av1.x;  As[(kb + 5) * 140 + pw] = av1.y;
        As[(kb + 6) * 140 + pw] = av1.z;  As[(kb + 7) * 140 + pw] = av1.w;
        Bs[(kb + 0) * 140 + pw] = bv0.x;  Bs[(kb + 1) * 140 + pw] = bv0.y;
        Bs[(kb + 2) * 140 + pw] = bv0.z;  Bs[(kb + 3) * 140 + pw] = bv0.w;
        Bs[(kb + 4) * 140 + pw] = bv1.x;  Bs[(kb + 5) * 140 + pw] = bv1.y;
        Bs[(kb + 6) * 140 + pw] = bv1.z;  Bs[(kb + 7) * 140 + pw] = bv1.w;
        __syncthreads();

#pragma unroll
        for (int kk = 0; kk < 16; ++kk) {
            float4 a0 = *(const float4*)&As[kk * 140 + pa];
            float4 a1 = *(const float4*)&As[kk * 140 + pa + 4];
            float4 b0 = *(const float4*)&Bs[kk * 140 + pb];
            float4 b1 = *(const float4*)&Bs[kk * 140 + pb + 4];
            float a[8]  = {a0.x, a0.y, a0.z, a0.w, a1.x, a1.y, a1.z, a1.w};
            float bb[8] = {b0.x, b0.y, b0.z, b0.w, b1.x, b1.y, b1.z, b1.w};
#pragma unroll
            for (int i = 0; i < 8; ++i)
#pragma unroll
                for (int j = 0; j < 8; ++j)
                    acc[i][j] = fmaf(a[i], bb[j], acc[i][j]);
        }
    }

    const int gcol  = n0 >> 10;              // gate for this whole block-column
    const int qbase = (n0 & 1023) + tx * 8;  // 4b+u base
    const int j0 = n0 + tx * 8;
    float bsv[8];
#pragma unroll
    for (int j = 0; j < 8; ++j) bsv[j] = bias1[j0 + j] + bias2[j0 + j];
#pragma unroll
    for (int i = 0; i < 8; ++i) {
        const size_t rowoff = (size_t)(m0 + ty * 8 + i) * 4096;
#pragma unroll
        for (int jj = 0; jj < 8; ++jj) {
            const int q = qbase + jj;
            C[rowoff + ((q >> 2) << 4) + (gcol << 2) + (q & 3)] = acc[i][jj] + bsv[jj];
        }
    }
}

// ---------------------------------------------------------------------------
// Fused layer-pipelined LSTM recurrence (one cooperative dispatch).
// 256 blocks x 256 threads. Tick tau: layer0 step tau, layer1 step tau-1.
// Weights are PINNED in VGPRs via an empty asm barrier after the one-time
// load (VGPR_Count must read ~240-256; at 128 the compiler was re-loading
// 196 KB/block/tick from L2 — the R0-R5 hidden bottleneck).
// Cross-block h transport: relaxed agent atomics (proven coherent). No fences.
// ---------------------------------------------------------------------------
__global__ void __launch_bounds__(256, 1) lstm_fused(
    const float* __restrict__ W_hh,  // [2][4096][1024]
    const float* __restrict__ W_ih,  // [2][4096][1024]
    const float* __restrict__ b_ih,  // [2][4096]
    const float* __restrict__ b_hh,  // [2][4096]
    const float* __restrict__ G,     // [2 br][T][4096] permuted layer-0 preacts
    const float* __restrict__ h1_0, const float* __restrict__ c1_0,
    const float* __restrict__ h2_0, const float* __restrict__ c2_0,
    float* __restrict__ hbuf,        // [2 buf][2 layer][2 br][1024]
    float* __restrict__ o_out,       // [2 br][1024]
    uint32_t* __restrict__ bar)
{
    const int b = blockIdx.x, t = threadIdx.x;
    const int row = t & 15, slice = t >> 4;
    const int gate = row >> 2, uoff = row & 3;
    const int j_glob = gate * 1024 + b * 4 + uoff;

    // ---- weights -> registers (rotated to match LDS traversal) ----
    float4 w0[16], w1h[16], w1i[16];
    {
        const float* r0 = W_hh + (size_t)j_glob * 1024 + slice * 64;
        const float* r1 = W_hh + 4194304ull + (size_t)j_glob * 1024 + slice * 64;
        const float* r2 = W_ih + 4194304ull + (size_t)j_glob * 1024 + slice * 64;
#pragma unroll
        for (int m = 0; m < 16; ++m) {
            const int o = ((m + slice) & 15) << 2;
            w0[m]  = *(const float4*)(r0 + o);
            w1h[m] = *(const float4*)(r1 + o);
            w1i[m] = *(const float4*)(r2 + o);
        }
    }
    // Pin: mark every weight component asm-defined so the loads cannot be
    // rematerialized inside the tick loop (forces register residency).
#pragma unroll
    for (int m = 0; m < 16; ++m) {
        asm volatile("" : "+v"(w0[m].x),  "+v"(w0[m].y),  "+v"(w0[m].z),  "+v"(w0[m].w),
                          "+v"(w1h[m].x), "+v"(w1h[m].y), "+v"(w1h[m].z), "+v"(w1h[m].w),
                          "+v"(w1i[m].x), "+v"(w1i[m].y), "+v"(w1i[m].z), "+v"(w1i[m].w));
    }

    __shared__ float hs[4096];        // [4 seg][1024]: seg = layer*2+br
    __shared__ float red[4][4][16];   // [wave][acc][row]
    __shared__ float bl1s[16];        // layer-1 bias for owned rows

    float creg = 0.f;
    if (t < 16) {
        const int layer = t >> 3, br = (t >> 2) & 1, u = t & 3;
        const float* cc = br ? c2_0 : c1_0;
        const float* hh = br ? h2_0 : h1_0;
        creg = cc[layer * 1024 + b * 4 + u];
        const float hinit = hh[layer * 1024 + b * 4 + u];
        __hip_atomic_store(&hbuf[4096 + layer * 2048 + br * 1024 + b * 4 + u],
                           hinit, __ATOMIC_RELAXED, __HIP_MEMORY_SCOPE_AGENT);
        if (layer == 1)
            __hip_atomic_store(&hbuf[2048 + br * 1024 + b * 4 + u],
                               hinit, __ATOMIC_RELAXED, __HIP_MEMORY_SCOPE_AGENT);
    }
    if (t >= 32 && t < 48) {
        const int rr = t & 15;
        const int jj = 4096 + (rr >> 2) * 1024 + b * 4 + (rr & 3);
        bl1s[rr] = b_ih[jj] + b_hh[jj];
    }
    if (t < 64) {
        asm volatile("s_waitcnt vmcnt(0)" ::: "memory");
        wave0_barrier(bar, 1u, t);
    }
    __syncthreads();

    for (int tick = 0; tick <= T_SEQ; ++tick) {
        // ---- stage h_prev (16 KB) LLC -> LDS via 64-bit relaxed agent
        // atomics (verified-coherent class, R4). Plane layout: identity map,
        // no transpose; ds_write_b64 stride-1 = 2-way aliasing = free. ----
        {
            const uint64_t* src64 = (const uint64_t*)(hbuf + ((tick + 1) & 1) * 4096);
            uint64_t v[8];
#pragma unroll
            for (int r = 0; r < 8; ++r)
                v[r] = __hip_atomic_load(src64 + t + r * 256, __ATOMIC_RELAXED,
                                         __HIP_MEMORY_SCOPE_AGENT);
            uint64_t* hs64 = (uint64_t*)hs;
#pragma unroll
            for (int r = 0; r < 8; ++r)
                hs64[t + r * 256] = v[r];
        }
        // ---- layer-0 G prefetch: lane t<32 gets row rr of branch t>>4 ----
        float gpre = 0.f;
        if (t < 32) {
            const int br = t >> 4, rr = t & 15;
            const int st = (tick < T_SEQ) ? tick : (T_SEQ - 1);
            gpre = G[((size_t)br * T_SEQ + st) * 4096 + b * 16 + rr];
        }
        __syncthreads();

        // ---- 3 matvecs over owned rows ----
        float a00 = 0.f, a01 = 0.f, a10 = 0.f, a11 = 0.f;
        const float4* H00 = (const float4*)hs;
        const float4* H01 = (const float4*)(hs + 1024);
        const float4* H10 = (const float4*)(hs + 2048);
        const float4* H11 = (const float4*)(hs + 3072);
#pragma unroll
        for (int m = 0; m < 16; ++m) {
            const int ci = (slice << 4) + ((m + slice) & 15);
            const float4 x0 = H00[ci], x1 = H01[ci];
            const float4 y0 = H10[ci], y1 = H11[ci];
            a00 = fmaf(w0[m].x, x0.x, a00); a00 = fmaf(w0[m].y, x0.y, a00);
            a00 = fmaf(w0[m].z, x0.z, a00); a00 = fmaf(w0[m].w, x0.w, a00);
            a01 = fmaf(w0[m].x, x1.x, a01); a01 = fmaf(w0[m].y, x1.y, a01);
            a01 = fmaf(w0[m].z, x1.z, a01); a01 = fmaf(w0[m].w, x1.w, a01);
            a10 = fmaf(w1i[m].x, x0.x, a10); a10 = fmaf(w1i[m].y, x0.y, a10);
            a10 = fmaf(w1i[m].z, x0.z, a10); a10 = fmaf(w1i[m].w, x0.w, a10);
            a10 = fmaf(w1h[m].x, y0.x, a10); a10 = fmaf(w1h[m].y, y0.y, a10);
            a10 = fmaf(w1h[m].z, y0.z, a10); a10 = fmaf(w1h[m].w, y0.w, a10);
            a11 = fmaf(w1i[m].x, x1.x, a11); a11 = fmaf(w1i[m].y, x1.y, a11);
            a11 = fmaf(w1i[m].z, x1.z, a11); a11 = fmaf(w1i[m].w, x1.w, a11);
            a11 = fmaf(w1h[m].x, y1.x, a11); a11 = fmaf(w1h[m].y, y1.y, a11);
            a11 = fmaf(w1h[m].z, y1.z, a11); a11 = fmaf(w1h[m].w, y1.w, a11);
        }
        a00 += __shfl_xor(a00, 16); a00 += __shfl_xor(a00, 32);
        a01 += __shfl_xor(a01, 16); a01 += __shfl_xor(a01, 32);
        a10 += __shfl_xor(a10, 16); a10 += __shfl_xor(a10, 32);
        a11 += __shfl_xor(a11, 16); a11 += __shfl_xor(a11, 32);
        const int wv = t >> 6, lane = t & 63;
        if (lane < 16) {
            red[wv][0][lane] = a00; red[wv][1][lane] = a01;
            red[wv][2][lane] = a10; red[wv][3][lane] = a11;
        }
        __syncthreads();

        // ---- tail: wave 0 only ----
        if (t < 64) {
            const int lb = t >> 4, rr = t & 15;
            float s = red[0][lb][rr] + red[1][lb][rr] + red[2][lb][rr] + red[3][lb][rr];
            s += (lb < 2) ? gpre : bl1s[rr];
            // lane lb*16+rr holds gate (rr>>2) of unit (rr&3), layer=lb>>1, br=lb&1
            const int src0 = ((t >> 2) << 4) + (t & 3);   // meaningful for t<16
            const float gi = __shfl(s, src0);
            const float gf = __shfl(s, src0 + 4);
            const float gg = __shfl(s, src0 + 8);
            const float go = __shfl(s, src0 + 12);
            if (t < 16) {
                const int layer = t >> 3, br = (t >> 2) & 1, u = t & 3;
                const bool active = (layer == 0) ? (tick < T_SEQ) : (tick >= 1);
                if (active) {
                    const float c = sigm(gf) * creg + sigm(gi) * ftanh(gg);
                    const float h = sigm(go) * ftanh(c);
                    creg = c;
                    __hip_atomic_store(&hbuf[(tick & 1) * 4096 + layer * 2048 + br * 1024 + b * 4 + u],
                                       h, __ATOMIC_RELAXED, __HIP_MEMORY_SCOPE_AGENT);
                    if (layer == 1 && tick == T_SEQ)
                        o_out[br * 1024 + b * 4 + u] = h;
                }
            }
            if (tick < T_SEQ) {
                asm volatile("s_waitcnt vmcnt(0)" ::: "memory");  // h at LLC
                wave0_barrier(bar, (uint32_t)tick + 2u, t);
            }
        }
        __syncthreads();
    }
}

// ---------------------------------------------------------------------------
// out = 5*exp(-sum |o1 - o2|)
// ---------------------------------------------------------------------------
__global__ void __launch_bounds__(256) dist_kernel(const float* __restrict__ o,
                                                   float* __restrict__ out)
{
    int t = threadIdx.x;
    float s = 0.f;
    for (int i = t; i < 1024; i += 256) s += fabsf(o[i] - o[i + 1024]);
#pragma unroll
    for (int off = 1; off < 64; off <<= 1) s += __shfl_xor(s, off);
    __shared__ float r[4];
    if ((t & 63) == 0) r[t >> 6] = s;
    __syncthreads();
    if (t == 0) out[0] = 5.0f * expf(-(r[0] + r[1] + r[2] + r[3]));
}

// ---------------------------------------------------------------------------
extern "C" void kernel_launch(void* const* d_in, const int* in_sizes, int n_in,
                              void* d_out, int out_size, void* d_ws, size_t ws_size,
                              hipStream_t stream) {
    const float* s1   = (const float*)d_in[0];
    const float* s2   = (const float*)d_in[1];
    const float* h1_0 = (const float*)d_in[2];
    const float* c1_0 = (const float*)d_in[3];
    const float* h2_0 = (const float*)d_in[4];
    const float* c2_0 = (const float*)d_in[5];
    const float* W_ih = (const float*)d_in[6];
    const float* W_hh = (const float*)d_in[7];
    const float* b_ih = (const float*)d_in[8];
    const float* b_hh = (const float*)d_in[9];

    uint8_t* w8 = (uint8_t*)d_ws;
    uint32_t* bar  = (uint32_t*)(w8);            // 8 KB barrier region
    float* hbuf  = (float*)(w8 + 8192);          // 32 KB: [2][2][2][1024]
    float* o_out = (float*)(w8 + 8192 + 32768);  // 8 KB:  [2][1024]
    float* G     = (float*)(w8 + 65536);         // 128 MB: [2][T][4096]

    hipMemsetAsync(d_ws, 0, 8192, stream);       // zero barrier counters

    // Phase 1: layer-0 input GEMM for both branches (permuted output)
    dim3 ggrid(32, 64);
    gemm_nt_bias<<<ggrid, 256, 0, stream>>>(s1, s2, W_ih, b_ih, b_hh, G);

    // Phase 2: fused layer-pipelined recurrence (single cooperative dispatch)
    {
        const float* whh = W_hh; const float* wih = W_ih;
        const float* bi = b_ih;  const float* bh = b_hh;
        const float* gg = G;
        const float* h1p = h1_0; const float* c1p = c1_0;
        const float* h2p = h2_0; const float* c2p = c2_0;
        float* hb = hbuf; float* oo = o_out; uint32_t* br = bar;
        void* args[] = { &whh, &wih, &bi, &bh, &gg,
                         &h1p, &c1p, &h2p, &c2p, &hb, &oo, &br };
        hipLaunchCooperativeKernel(lstm_fused, dim3(256), dim3(256), args, 0, stream);
    }

    // Phase 3: scalar output
    dist_kernel<<<1, 256, 0, stream>>>(o_out, (float*)d_out);
}